// Round 3
// baseline (323.300 us; speedup 1.0000x reference)
//
#include <hip/hip_runtime.h>
#include <hip/hip_bf16.h>
#include <cstddef>

#define D_DIM 768
#define V_DIM 10240
#define ROWS  32768           // B*N = 8*4096
#define BN    96              // col-stripe per block (8 stripes cover 768)
#define PR    256             // rows per panel (8 waves x 32)
#define PANELS 4              // panels per block -> 1024 rows per block
#define KTILES 24             // 768 / 32

using bf16x8 = __attribute__((ext_vector_type(8))) __bf16;
using f32x4  = __attribute__((ext_vector_type(4))) float;

// ---------------------------------------------------------------------------
// Pre-pass: fold permutation + 2*(x-0.5) affine into weights.
// W'[d][j] = 2 * W[d][perm(j)],  perm(j) = (j%3)*256 + (j/48)*16 + (j/3)%16
// bias[d]  = -sum_k W[d][k]
// ---------------------------------------------------------------------------
__global__ void prep_w(const float* __restrict__ W, __bf16* __restrict__ Wp,
                       float* __restrict__ bias) {
    __shared__ float row[D_DIM];
    __shared__ float red[256];
    const int d = blockIdx.x;
    const int t = threadIdx.x;
    float s = 0.f;
    for (int k = t; k < D_DIM; k += 256) {
        float w = W[(size_t)d * D_DIM + k];
        row[k] = w;
        s += w;
    }
    red[t] = s;
    __syncthreads();
    for (int off = 128; off > 0; off >>= 1) {
        if (t < off) red[t] += red[t + off];
        __syncthreads();
    }
    if (t == 0) bias[d] = -red[0];
    for (int j = t; j < D_DIM; j += 256) {
        int c  = j % 3;
        int pw = (j / 3) & 15;
        int ph = j / 48;
        Wp[(size_t)d * D_DIM + j] = (__bf16)(2.0f * row[c * 256 + ph * 16 + pw]);
    }
}

// ---------------------------------------------------------------------------
// B-resident GEMM. 256 persistent blocks (1/CU), 8 waves (512 thr).
//  - Block owns col-stripe n0..n0+95, ALL of K: B in LDS (144 KB), loaded ONCE.
//  - K-loop has NO barriers, NO staging: waves fully independent.
//  - A (fp32 X) loaded straight to registers (coalesced 128B lines/row),
//    converted to bf16 in-register. Compiler pipelines freely (no barriers).
//  - LDS swizzle: 16B-unit u' = u ^ (row&7); inverse-swizzled gload_lds source,
//    swizzled ds_read -> 2 lanes/bank (free).
//  - XCD grouping: x = b&7 selects row-range; all 8 col-stripes of that range
//    sit on one XCD so the 8x X re-read is L2-served; HBM reads X once.
// ---------------------------------------------------------------------------
__launch_bounds__(512, 2)
__global__ void gemm_resident(const float* __restrict__ X, const __bf16* __restrict__ Wp,
                              const float* __restrict__ bias, const float* __restrict__ ptab,
                              const int* __restrict__ coord, const int* __restrict__ valid,
                              float* __restrict__ out0, float* __restrict__ out1,
                              float* __restrict__ out2) {
    __shared__ __align__(16) __bf16 lb[BN * D_DIM];   // 144 KB

    const int tid  = threadIdx.x;
    const int lane = tid & 63;
    const int wave = tid >> 6;
    const int lr   = lane & 15;
    const int qh   = lane >> 4;          // k-quarter (16B unit within 64B)

    // block -> (stripe, rowblk), XCD-grouped: XCD x hosts rowblks 4x..4x+3
    // for ALL 8 stripes.
    const int b      = blockIdx.x;
    const int x      = b & 7;
    const int i      = b >> 3;           // 0..31
    const int stripe = i & 7;
    const int rowblk = x * 4 + (i >> 3);
    const int n0     = stripe * BN;
    const size_t mbase = (size_t)rowblk * (PR * PANELS);   // 1024 rows / block

    // ---- stage B once: 96 rows x 96 16B-units, 18 gload_lds per thread ----
    #pragma unroll
    for (int u = 0; u < 18; ++u) {
        int q   = u * 512 + tid;         // 0..9215
        int row = q / 96;
        int un  = q - row * 96;
        int su  = un ^ (row & 7);        // inverse swizzle on the SOURCE
        const __bf16* src = Wp + (size_t)(n0 + row) * D_DIM + su * 8;
        __builtin_amdgcn_global_load_lds(
            (const __attribute__((address_space(1))) void*)src,
            (__attribute__((address_space(3))) void*)&lb[q * 8], 16, 0, 0);
    }

    // ---- aux outputs while B-loads fly (stripe 0 owns its 1024 rows) ----
    if (stripe == 0) {
        #pragma unroll
        for (int t = 0; t < 2; ++t) {
            size_t m = mbase + t * 512 + tid;
            int c0 = coord[2 * m];
            int c1 = coord[2 * m + 1];
            out1[2 * m]     = (float)c1;
            out1[2 * m + 1] = (float)c0;
            out2[m] = valid[m] ? 0.0f : 1.0f;
        }
    }

    float bv[6];
    #pragma unroll
    for (int j = 0; j < 6; ++j)
        bv[j] = bias[n0 + j * 16 + lr];

    // hoisted B read bases: row = j*16+lr
    int brow[6], bx7[6];
    #pragma unroll
    for (int j = 0; j < 6; ++j) {
        int row = j * 16 + lr;
        brow[j] = row * D_DIM;           // bf16-elem base of the row
        bx7[j]  = row & 7;
    }

    __syncthreads();   // the ONLY block-wide barrier

    const float* pt0 = ptab;
    const float* pt1 = ptab + (size_t)V_DIM * D_DIM;

    for (int p = 0; p < PANELS; ++p) {
        const size_t m0 = mbase + (size_t)p * PR;
        const size_t wrow = m0 + wave * 32;

        const float* a0 = X + (wrow + lr) * D_DIM + qh * 8;
        const float* a1 = a0 + (size_t)16 * D_DIM;

        f32x4 acc[2][6] = {};

        #pragma unroll 8
        for (int kt = 0; kt < KTILES; ++kt) {
            const float4 f00 = *(const float4*)(a0 + kt * 32);
            const float4 f01 = *(const float4*)(a0 + kt * 32 + 4);
            const float4 f10 = *(const float4*)(a1 + kt * 32);
            const float4 f11 = *(const float4*)(a1 + kt * 32 + 4);
            bf16x8 af0, af1;
            af0[0] = (__bf16)f00.x; af0[1] = (__bf16)f00.y;
            af0[2] = (__bf16)f00.z; af0[3] = (__bf16)f00.w;
            af0[4] = (__bf16)f01.x; af0[5] = (__bf16)f01.y;
            af0[6] = (__bf16)f01.z; af0[7] = (__bf16)f01.w;
            af1[0] = (__bf16)f10.x; af1[1] = (__bf16)f10.y;
            af1[2] = (__bf16)f10.z; af1[3] = (__bf16)f10.w;
            af1[4] = (__bf16)f11.x; af1[5] = (__bf16)f11.y;
            af1[6] = (__bf16)f11.z; af1[7] = (__bf16)f11.w;

            const int ku = (kt << 2) | qh;
            #pragma unroll
            for (int j = 0; j < 6; ++j) {
                const int un = ku ^ bx7[j];
                const bf16x8 bfv = *(const bf16x8*)&lb[brow[j] + un * 8];
                acc[0][j] = __builtin_amdgcn_mfma_f32_16x16x32_bf16(af0, bfv, acc[0][j], 0, 0, 0);
                acc[1][j] = __builtin_amdgcn_mfma_f32_16x16x32_bf16(af1, bfv, acc[1][j], 0, 0, 0);
            }
        }

        // ---- epilogue for this panel: bias + pos add + store ----
        #pragma unroll
        for (int ii = 0; ii < 2; ++ii) {
            #pragma unroll
            for (int r = 0; r < 4; ++r) {
                const size_t m = wrow + ii * 16 + qh * 4 + r;
                int c0 = coord[2 * m];
                int c1 = coord[2 * m + 1];
                if (c0 < 0) c0 = 0;
                if (c1 < 0) c1 = 0;
                const int vld = valid[m];
                const float* p0 = pt0 + (size_t)c1 * D_DIM + n0;
                const float* p1 = pt1 + (size_t)c0 * D_DIM + n0;
                float* orow = out0 + m * D_DIM + n0;
                #pragma unroll
                for (int j = 0; j < 6; ++j) {
                    const int d = j * 16 + lr;
                    float v = acc[ii][j][r] + bv[j];
                    if (vld)
                        v += p0[d] + p1[d];
                    orow[d] = v;
                }
            }
        }
    }
}

extern "C" void kernel_launch(void* const* d_in, const int* in_sizes, int n_in,
                              void* d_out, int out_size, void* d_ws, size_t ws_size,
                              hipStream_t stream) {
    const float* x     = (const float*)d_in[0];
    const int*   coord = (const int*)d_in[1];
    const int*   valid = (const int*)d_in[2];
    const float* W     = (const float*)d_in[3];
    const float* ptab  = (const float*)d_in[4];

    float* out0 = (float*)d_out;                  // [32768][768]
    float* out1 = out0 + (size_t)ROWS * D_DIM;    // [32768][2]
    float* out2 = out1 + (size_t)ROWS * 2;        // [32768]

    // Workspace: [Wp bf16 1.125 MB][bias 3 KB]
    __bf16* Wp   = (__bf16*)d_ws;
    float*  bias = (float*)((char*)d_ws + (size_t)D_DIM * D_DIM * sizeof(__bf16));

    hipLaunchKernelGGL(prep_w, dim3(D_DIM), dim3(256), 0, stream, W, Wp, bias);
    hipLaunchKernelGGL(gemm_resident, dim3(256), dim3(512), 0, stream,
                       x, Wp, bias, ptab, coord, valid, out0, out1, out2);
}

// Round 4
// 274.302 us; speedup vs baseline: 1.1786x; 1.1786x over previous
//
#include <hip/hip_runtime.h>
#include <hip/hip_bf16.h>
#include <cstddef>

#define D_DIM 768
#define V_DIM 10240
#define ROWS 32768   // B*N = 8*4096
#define BM 128
#define BN 128
#define BK 32

using bf16x8 = __attribute__((ext_vector_type(8))) __bf16;
using f32x4  = __attribute__((ext_vector_type(4))) float;

// ---------------------------------------------------------------------------
// Pre-pass: fold permutation + 2*(x-0.5) affine into weights.
// W'[d][j] = 2 * W[d][perm(j)],  perm(j) = (j%3)*256 + (j/48)*16 + (j/3)%16
// bias[d]  = -sum_k W[d][k]
// ---------------------------------------------------------------------------
__global__ void prep_w(const float* __restrict__ W, __bf16* __restrict__ Wp,
                       float* __restrict__ bias) {
    __shared__ float row[D_DIM];
    __shared__ float red[256];
    const int d = blockIdx.x;
    const int t = threadIdx.x;
    float s = 0.f;
    for (int k = t; k < D_DIM; k += 256) {
        float w = W[(size_t)d * D_DIM + k];
        row[k] = w;
        s += w;
    }
    red[t] = s;
    __syncthreads();
    for (int off = 128; off > 0; off >>= 1) {
        if (t < off) red[t] += red[t + off];
        __syncthreads();
    }
    if (t == 0) bias[d] = -red[0];
    for (int j = t; j < D_DIM; j += 256) {
        int c  = j % 3;
        int pw = (j / 3) & 15;
        int ph = j / 48;
        Wp[(size_t)d * D_DIM + j] = (__bf16)(2.0f * row[c * 256 + ph * 16 + pw]);
    }
}

// ---------------------------------------------------------------------------
// Streaming prepass: x fp32 -> bf16 (8 elems/thread), fused aux outputs.
// ---------------------------------------------------------------------------
__global__ void conv_aux(const float* __restrict__ X, __bf16* __restrict__ Xb,
                         const int* __restrict__ coord, const int* __restrict__ valid,
                         float* __restrict__ out1, float* __restrict__ out2) {
    int i = blockIdx.x * blockDim.x + threadIdx.x;
    size_t base = (size_t)i * 8;
    const float4* src = (const float4*)(X + base);
    float4 f0 = src[0];
    float4 f1 = src[1];
    bf16x8 v;
    v[0] = (__bf16)f0.x; v[1] = (__bf16)f0.y; v[2] = (__bf16)f0.z; v[3] = (__bf16)f0.w;
    v[4] = (__bf16)f1.x; v[5] = (__bf16)f1.y; v[6] = (__bf16)f1.z; v[7] = (__bf16)f1.w;
    *(bf16x8*)(Xb + base) = v;

    if (i < ROWS) {
        int c0 = coord[2 * i];
        int c1 = coord[2 * i + 1];
        out1[2 * i]     = (float)c1;
        out1[2 * i + 1] = (float)c0;
        out2[i] = valid[i] ? 0.0f : 1.0f;
    }
}

// ---------------------------------------------------------------------------
// Aux-only kernel (fallback path when ws can't hold bf16 X).
// ---------------------------------------------------------------------------
__global__ void aux_out(const int* __restrict__ coord, const int* __restrict__ valid,
                        float* __restrict__ out1, float* __restrict__ out2) {
    int i = blockIdx.x * blockDim.x + threadIdx.x;
    if (i < ROWS) {
        int c0 = coord[2 * i];
        int c1 = coord[2 * i + 1];
        out1[2 * i]     = (float)c1;
        out1[2 * i + 1] = (float)c0;
        out2[i] = valid[i] ? 0.0f : 1.0f;
    }
}

// ---------------------------------------------------------------------------
// Fast GEMM (round-0 structure + two fixes):
//  1) LDS bank-conflict swizzle: 16B-unit u_phys = u_logical ^ ((row>>1)&3).
//     Applied to the global_load_lds SOURCE (linear LDS dest) and to the
//     ds_read offsets — proven 0-conflict in rounds 1-2 on this tile shape.
//  2) XCD grouping: id&7 -> XCD; XCD x owns row panels 32x..32x+31, with all
//     6 col-blocks of a panel consecutive -> X panel re-reads are L2 hits.
// 128x128 tile, BK=32, 4 waves (2x2 of 64x64), 16x16x32 bf16 MFMA, 4x4 acc.
// ---------------------------------------------------------------------------
__launch_bounds__(256)
__global__ void gemm_fast(const __bf16* __restrict__ Xb, const __bf16* __restrict__ Wp,
                          const float* __restrict__ bias, const float* __restrict__ ptab,
                          const int* __restrict__ coord, const int* __restrict__ valid,
                          float* __restrict__ out) {
    __shared__ __align__(16) __bf16 la[BM * BK];
    __shared__ __align__(16) __bf16 lb[BN * BK];

    // XCD-grouped block -> (panel, col) mapping. Grid = 1536 = 8 XCD x 192.
    const int id  = blockIdx.x;
    const int xcd = id & 7;
    const int j6  = id >> 3;           // 0..191
    const int p   = xcd * 32 + j6 / 6; // row panel 0..255
    const int c   = j6 % 6;            // col block 0..5
    const int m0  = p * BM;
    const int n0  = c * BN;

    const int tid  = threadIdx.x;
    const int lane = tid & 63;
    const int wave = tid >> 6;
    const int wr   = (wave >> 1) * 64;
    const int wc   = (wave & 1) * 64;
    const int lr   = lane & 15;
    const int qh   = lane >> 4;        // logical 16B k-unit (0..3)

    // Staging descriptors: two 16B units per thread per matrix.
    // Physical unit q = i*256+tid; row = q>>2, u_phys = q&3,
    // source logical unit = u_phys ^ ((row>>1)&3).
    const __bf16* srcA[2];
    const __bf16* srcB[2];
    int dst[2];
    #pragma unroll
    for (int i = 0; i < 2; ++i) {
        int q   = i * 256 + tid;
        int row = q >> 2;
        int un  = (q & 3) ^ ((row >> 1) & 3);
        srcA[i] = Xb + (size_t)(m0 + row) * D_DIM + un * 8;
        srcB[i] = Wp + (size_t)(n0 + row) * D_DIM + un * 8;
        dst[i]  = q * 8;     // linear LDS dest (bf16 elems)
    }

    // Swizzled fragment read offsets.
    int aoff[4], boff[4];
    #pragma unroll
    for (int i = 0; i < 4; ++i) {
        int rowa = wr + i * 16 + lr;
        aoff[i] = rowa * BK + ((qh ^ ((rowa >> 1) & 3)) * 8);
        int rowb = wc + i * 16 + lr;
        boff[i] = rowb * BK + ((qh ^ ((rowb >> 1) & 3)) * 8);
    }

    f32x4 acc[4][4] = {};

    for (int kt = 0; kt < D_DIM / BK; ++kt) {
        const int k0 = kt * BK;

        #pragma unroll
        for (int i = 0; i < 2; ++i) {
            __builtin_amdgcn_global_load_lds(
                (const __attribute__((address_space(1))) void*)(srcA[i] + k0),
                (__attribute__((address_space(3))) void*)&la[dst[i]], 16, 0, 0);
            __builtin_amdgcn_global_load_lds(
                (const __attribute__((address_space(1))) void*)(srcB[i] + k0),
                (__attribute__((address_space(3))) void*)&lb[dst[i]], 16, 0, 0);
        }

        __syncthreads();

        bf16x8 af[4], bfr[4];
        #pragma unroll
        for (int i = 0; i < 4; ++i)
            af[i] = *(const bf16x8*)&la[aoff[i]];
        #pragma unroll
        for (int j = 0; j < 4; ++j)
            bfr[j] = *(const bf16x8*)&lb[boff[j]];

        #pragma unroll
        for (int i = 0; i < 4; ++i)
            #pragma unroll
            for (int j = 0; j < 4; ++j)
                acc[i][j] = __builtin_amdgcn_mfma_f32_16x16x32_bf16(af[i], bfr[j], acc[i][j], 0, 0, 0);

        __syncthreads();
    }

    const float* pt0 = ptab;
    const float* pt1 = ptab + (size_t)V_DIM * D_DIM;
    const int rq = (lane >> 4) * 4;

    float bvals[4];
    #pragma unroll
    for (int j = 0; j < 4; ++j)
        bvals[j] = bias[n0 + wc + j * 16 + lr];

    #pragma unroll
    for (int i = 0; i < 4; ++i) {
        #pragma unroll
        for (int r = 0; r < 4; ++r) {
            int m = m0 + wr + i * 16 + rq + r;
            int c0 = coord[2 * m];
            int c1 = coord[2 * m + 1];
            if (c0 < 0) c0 = 0;
            if (c1 < 0) c1 = 0;
            int vld = valid[m];
            #pragma unroll
            for (int j = 0; j < 4; ++j) {
                int d = n0 + wc + j * 16 + lr;
                float v = acc[i][j][r] + bvals[j];
                if (vld)
                    v += pt0[(size_t)c1 * D_DIM + d] + pt1[(size_t)c0 * D_DIM + d];
                out[(size_t)m * D_DIM + d] = v;
            }
        }
    }
}

// ---------------------------------------------------------------------------
// Fallback GEMM (fp32 X staged through registers) — round-0 structure.
// ---------------------------------------------------------------------------
__launch_bounds__(256)
__global__ void gemm_slow(const float* __restrict__ X, const __bf16* __restrict__ Wp,
                          const float* __restrict__ bias, const float* __restrict__ ptab,
                          const int* __restrict__ coord, const int* __restrict__ valid,
                          float* __restrict__ out) {
    __shared__ __align__(16) __bf16 la[BM * BK];
    __shared__ __align__(16) __bf16 lb[BN * BK];

    const int n0 = blockIdx.x * BN;
    const int m0 = blockIdx.y * BM;

    const int tid  = threadIdx.x;
    const int lane = tid & 63;
    const int wave = tid >> 6;
    const int wr   = (wave >> 1) * 64;
    const int wc   = (wave & 1) * 64;
    const int lr   = lane & 15;
    const int kq   = (lane >> 4) * 8;

    f32x4 acc[4][4] = {};

    for (int kt = 0; kt < D_DIM / BK; ++kt) {
        const int k0 = kt * BK;

        #pragma unroll
        for (int i = 0; i < 2; ++i) {
            int idx = i * 2048 + tid * 8;
            int row = idx >> 5;
            int col = idx & 31;
            const __bf16* src = Wp + (size_t)(n0 + row) * D_DIM + k0 + col;
            __builtin_amdgcn_global_load_lds(
                (const __attribute__((address_space(1))) void*)src,
                (__attribute__((address_space(3))) void*)&lb[idx], 16, 0, 0);
        }

        #pragma unroll
        for (int i = 0; i < 2; ++i) {
            int idx = i * 2048 + tid * 8;
            int row = idx >> 5;
            int col = idx & 31;
            const float4* src = (const float4*)(X + (size_t)(m0 + row) * D_DIM + k0 + col);
            float4 f0 = src[0];
            float4 f1 = src[1];
            bf16x8 v;
            v[0] = (__bf16)f0.x; v[1] = (__bf16)f0.y; v[2] = (__bf16)f0.z; v[3] = (__bf16)f0.w;
            v[4] = (__bf16)f1.x; v[5] = (__bf16)f1.y; v[6] = (__bf16)f1.z; v[7] = (__bf16)f1.w;
            *(bf16x8*)&la[idx] = v;
        }

        __syncthreads();

        bf16x8 af[4], bfr[4];
        #pragma unroll
        for (int i = 0; i < 4; ++i)
            af[i] = *(const bf16x8*)&la[(wr + i * 16 + lr) * BK + kq];
        #pragma unroll
        for (int j = 0; j < 4; ++j)
            bfr[j] = *(const bf16x8*)&lb[(wc + j * 16 + lr) * BK + kq];

        #pragma unroll
        for (int i = 0; i < 4; ++i)
            #pragma unroll
            for (int j = 0; j < 4; ++j)
                acc[i][j] = __builtin_amdgcn_mfma_f32_16x16x32_bf16(af[i], bfr[j], acc[i][j], 0, 0, 0);

        __syncthreads();
    }

    const float* pt0 = ptab;
    const float* pt1 = ptab + (size_t)V_DIM * D_DIM;
    const int rq = (lane >> 4) * 4;

    float bvals[4];
    #pragma unroll
    for (int j = 0; j < 4; ++j)
        bvals[j] = bias[n0 + wc + j * 16 + lr];

    #pragma unroll
    for (int i = 0; i < 4; ++i) {
        #pragma unroll
        for (int r = 0; r < 4; ++r) {
            int m = m0 + wr + i * 16 + rq + r;
            int c0 = coord[2 * m];
            int c1 = coord[2 * m + 1];
            if (c0 < 0) c0 = 0;
            if (c1 < 0) c1 = 0;
            int vld = valid[m];
            #pragma unroll
            for (int j = 0; j < 4; ++j) {
                int d = n0 + wc + j * 16 + lr;
                float v = acc[i][j][r] + bvals[j];
                if (vld)
                    v += pt0[(size_t)c1 * D_DIM + d] + pt1[(size_t)c0 * D_DIM + d];
                out[(size_t)m * D_DIM + d] = v;
            }
        }
    }
}

extern "C" void kernel_launch(void* const* d_in, const int* in_sizes, int n_in,
                              void* d_out, int out_size, void* d_ws, size_t ws_size,
                              hipStream_t stream) {
    const float* x     = (const float*)d_in[0];
    const int*   coord = (const int*)d_in[1];
    const int*   valid = (const int*)d_in[2];
    const float* W     = (const float*)d_in[3];
    const float* ptab  = (const float*)d_in[4];

    float* out0 = (float*)d_out;                       // [32768][768]
    float* out1 = out0 + (size_t)ROWS * D_DIM;         // [32768][2]
    float* out2 = out1 + (size_t)ROWS * 2;             // [32768]

    // Workspace layout: [Xb bf16 48MB][Wp bf16 1.125MB][bias 3KB]
    const size_t xb_bytes = (size_t)ROWS * D_DIM * sizeof(__bf16);
    const size_t wp_bytes = (size_t)D_DIM * D_DIM * sizeof(__bf16);
    const size_t need = xb_bytes + wp_bytes + D_DIM * sizeof(float);

    if (ws_size >= need) {
        __bf16* Xb  = (__bf16*)d_ws;
        __bf16* Wp  = (__bf16*)((char*)d_ws + xb_bytes);
        float* bias = (float*)((char*)d_ws + xb_bytes + wp_bytes);

        hipLaunchKernelGGL(prep_w, dim3(D_DIM), dim3(256), 0, stream, W, Wp, bias);
        hipLaunchKernelGGL(conv_aux, dim3((ROWS * D_DIM / 8) / 256), dim3(256), 0, stream,
                           x, Xb, coord, valid, out1, out2);
        hipLaunchKernelGGL(gemm_fast, dim3((ROWS / BM) * (D_DIM / BN)), dim3(256), 0, stream,
                           Xb, Wp, bias, ptab, coord, valid, out0);
    } else {
        __bf16* Wp  = (__bf16*)d_ws;
        float* bias = (float*)((char*)d_ws + wp_bytes);

        hipLaunchKernelGGL(prep_w, dim3(D_DIM), dim3(256), 0, stream, W, Wp, bias);
        hipLaunchKernelGGL(aux_out, dim3(ROWS / 256), dim3(256), 0, stream, coord, valid, out1, out2);
        hipLaunchKernelGGL(gemm_slow, dim3(D_DIM / BN, ROWS / BM), dim3(256), 0, stream,
                           x, Wp, bias, ptab, coord, valid, out0);
    }
}